// Round 1
// baseline (3091.718 us; speedup 1.0000x reference)
//
#include <hip/hip_runtime.h>
#include <math.h>

#define D 128

// ---------------------------------------------------------------- degree
__global__ void k_deg(const int* __restrict__ dst, int* __restrict__ deg, int E) {
    int e = blockIdx.x * 256 + threadIdx.x;
    if (e < E) atomicAdd(&deg[dst[e]], 1);
}

__global__ void k_invdeg(const int* __restrict__ deg, float* __restrict__ invd, int n) {
    int i = blockIdx.x * 256 + threadIdx.x;
    if (i < n) invd[i] = 1.0f / (float)max(deg[i], 1);
}

// ---------------------------------------------------------------- scatter-add aggregation
// one wave per edge: 64 lanes x float2 = 128 dims
__global__ void k_scatter(const float* __restrict__ x, const int* __restrict__ src,
                          const int* __restrict__ dst, float* agg, int E) {
    long long gid = (long long)blockIdx.x * 256 + threadIdx.x;
    int e = (int)(gid >> 6);
    if (e >= E) return;
    int lane = (int)(gid & 63);
    int s = src[e], d = dst[e];
    const float2 v = *(const float2*)(x + (size_t)s * D + lane * 2);
    float* a = agg + (size_t)d * D + lane * 2;
    atomicAdd(a, v.x);
    atomicAdd(a + 1, v.y);
}

// ---------------------------------------------------------------- weight concat: Wcat[k][j], k<128 -> Wl[j][k], else Wr[j][k-128]
__global__ void k_prepw(const float* __restrict__ Wl, const float* __restrict__ Wr,
                        float* __restrict__ Wcat, int OUT) {
    int idx = blockIdx.x * 256 + threadIdx.x;
    if (idx >= 256 * OUT) return;
    int k = idx / OUT, j = idx - k * OUT;
    Wcat[idx] = (k < D) ? Wl[j * D + k] : Wr[j * D + (k - D)];
}

// ---------------------------------------------------------------- fused linear
// C[m][j] = sum_k Avirt[m][k] * Wcat[k][j] + b[j], Avirt = [agg*invdeg | xin]
// TILE_M = 64 nodes, TILE_N = 16*JT outputs (covers full OUT -> out may alias agg)
template<int OUT, int JT, bool RELU>
__global__ __launch_bounds__(256) void k_gemm(
    const float* agg, const float* __restrict__ xin,
    const float* __restrict__ invd, const float* __restrict__ Wcat,
    const float* __restrict__ bias, float* out, int nN)
{
    constexpr int TN = 16 * JT;
    __shared__ float As[64][65];      // [k][m], +1 pad
    __shared__ float Ws[64][TN];      // [k][j]
    const int tid = threadIdx.x;
    const int tx = tid & 15, ty = tid >> 4;
    const int m0 = blockIdx.x * 64;

    float acc[4][JT];
#pragma unroll
    for (int i = 0; i < 4; ++i)
#pragma unroll
        for (int u = 0; u < JT; ++u) acc[i][u] = 0.f;

    for (int kc = 0; kc < 4; ++kc) {
        const int k0 = kc * 64;
        // stage A (transposed): As[kk][mm] = Avirt[m0+mm][k0+kk]
#pragma unroll
        for (int p = 0; p < 16; ++p) {
            int idx = tid + p * 256;           // 0..4095
            int mm = idx >> 6, kk = idx & 63;
            int node = m0 + mm;
            float v = 0.f;
            if (node < nN) {
                int k = k0 + kk;
                if (k < D) v = agg[(size_t)node * D + k] * invd[node];
                else       v = xin[(size_t)node * D + (k - D)];
            }
            As[kk][mm] = v;
        }
        // stage W: Ws[kk][j] (zero-pad j >= OUT)
        for (int idx = tid; idx < 64 * TN; idx += 256) {
            int kk = idx / TN, j = idx - kk * TN;
            Ws[kk][j] = (j < OUT) ? Wcat[(size_t)(k0 + kk) * OUT + j] : 0.f;
        }
        __syncthreads();
#pragma unroll
        for (int kk = 0; kk < 64; ++kk) {
            float a[4];
#pragma unroll
            for (int i = 0; i < 4; ++i) a[i] = As[kk][ty * 4 + i];
#pragma unroll
            for (int u = 0; u < JT; ++u) {
                float w = Ws[kk][tx + 16 * u];
#pragma unroll
                for (int i = 0; i < 4; ++i) acc[i][u] += a[i] * w;
            }
        }
        __syncthreads();
    }
    // epilogue (writes only to this block's own rows -> agg-alias safe)
#pragma unroll
    for (int i = 0; i < 4; ++i) {
        int m = m0 + ty * 4 + i;
        if (m >= nN) continue;
#pragma unroll
        for (int u = 0; u < JT; ++u) {
            int j = tx + 16 * u;
            if (j < OUT) {
                float v = acc[i][u] + bias[j];
                if (RELU) v = fmaxf(v, 0.f);
                out[(size_t)m * OUT + j] = v;
            }
        }
    }
}

// ---------------------------------------------------------------- log_softmax over 40 cols, one wave per row
__global__ void k_logsoftmax(float* out, int nN) {
    int row = blockIdx.x * 4 + (threadIdx.x >> 6);
    int lane = threadIdx.x & 63;
    if (row >= nN) return;
    float v = (lane < 40) ? out[(size_t)row * 40 + lane] : -INFINITY;
    float mx = v;
#pragma unroll
    for (int o = 32; o; o >>= 1) mx = fmaxf(mx, __shfl_xor(mx, o));
    float e = (lane < 40) ? expf(v - mx) : 0.f;
    float s = e;
#pragma unroll
    for (int o = 32; o; o >>= 1) s += __shfl_xor(s, o);
    if (lane < 40) out[(size_t)row * 40 + lane] = v - mx - logf(s);
}

// ---------------------------------------------------------------- launch
extern "C" void kernel_launch(void* const* d_in, const int* in_sizes, int n_in,
                              void* d_out, int out_size, void* d_ws, size_t ws_size,
                              hipStream_t stream) {
    const float* x   = (const float*)d_in[0];
    const int*   ei  = (const int*)d_in[1];
    const float* Wl0 = (const float*)d_in[2];
    const float* Wr0 = (const float*)d_in[3];
    const float* b0  = (const float*)d_in[4];
    const float* Wl1 = (const float*)d_in[5];
    const float* Wr1 = (const float*)d_in[6];
    const float* b1  = (const float*)d_in[7];
    const float* Wl2 = (const float*)d_in[8];
    const float* Wr2 = (const float*)d_in[9];
    const float* b2  = (const float*)d_in[10];
    const int nN = in_sizes[0] / D;
    const int E  = in_sizes[1] / 2;
    const int* src = ei;
    const int* dst = ei + E;

    char* w = (char*)d_ws;
    auto alloc = [&](size_t bytes) { char* p = w; w += (bytes + 255) & ~(size_t)255; return p; };
    int*   deg  = (int*)  alloc((size_t)nN * 4);
    float* invd = (float*)alloc((size_t)nN * 4);
    float* bufA = (float*)alloc((size_t)nN * D * 4);
    float* bufB = (float*)alloc((size_t)nN * D * 4);
    float* wcat = (float*)alloc((size_t)256 * 128 * 4);
    float* logits = (float*)d_out;

    const int SCAT_BLKS = (int)(((long long)E * 64 + 255) / 256);
    const int GEMM_BLKS = (nN + 63) / 64;

    // degrees (shared by all layers)
    hipMemsetAsync(deg, 0, (size_t)nN * 4, stream);
    k_deg<<<(E + 255) / 256, 256, 0, stream>>>(dst, deg, E);
    k_invdeg<<<(nN + 255) / 256, 256, 0, stream>>>(deg, invd, nN);

    // ---- layer 0: agg(x)->bufA ; h0 = relu(lin) -> bufB
    hipMemsetAsync(bufA, 0, (size_t)nN * D * 4, stream);
    k_scatter<<<SCAT_BLKS, 256, 0, stream>>>(x, src, dst, bufA, E);
    k_prepw<<<(256 * 128 + 255) / 256, 256, 0, stream>>>(Wl0, Wr0, wcat, 128);
    k_gemm<128, 8, true><<<GEMM_BLKS, 256, 0, stream>>>(bufA, x, invd, wcat, b0, bufB, nN);

    // ---- layer 1: agg(h0)->bufA ; h1 = relu(lin) -> bufA (alias-safe)
    hipMemsetAsync(bufA, 0, (size_t)nN * D * 4, stream);
    k_scatter<<<SCAT_BLKS, 256, 0, stream>>>(bufB, src, dst, bufA, E);
    k_prepw<<<(256 * 128 + 255) / 256, 256, 0, stream>>>(Wl1, Wr1, wcat, 128);
    k_gemm<128, 8, true><<<GEMM_BLKS, 256, 0, stream>>>(bufA, bufB, invd, wcat, b1, bufA, nN);

    // ---- layer 2: agg(h1)->bufB ; logits = lin -> d_out ; log_softmax in place
    hipMemsetAsync(bufB, 0, (size_t)nN * D * 4, stream);
    k_scatter<<<SCAT_BLKS, 256, 0, stream>>>(bufA, src, dst, bufB, E);
    k_prepw<<<(256 * 40 + 255) / 256, 256, 0, stream>>>(Wl2, Wr2, wcat, 40);
    k_gemm<40, 3, false><<<GEMM_BLKS, 256, 0, stream>>>(bufB, bufA, invd, wcat, b2, logits, nN);
    k_logsoftmax<<<(nN + 3) / 4, 256, 0, stream>>>(logits, nN);
}

// Round 2
// 1245.132 us; speedup vs baseline: 2.4830x; 2.4830x over previous
//
#include <hip/hip_runtime.h>
#include <math.h>

#define D 128

// ---------------------------------------------------------------- degree histogram
__global__ void k_deg(const int* __restrict__ dst, int* __restrict__ deg, int E) {
    int e = blockIdx.x * 256 + threadIdx.x;
    if (e < E) atomicAdd(&deg[dst[e]], 1);
}

// ---------------------------------------------------------------- scan step 1: per-block exclusive scan + block totals
__global__ void k_scan1(const int* __restrict__ deg, int* __restrict__ rowptr,
                        int* __restrict__ bsum, int nN) {
    __shared__ int s[256];
    int tid = threadIdx.x;
    int i = blockIdx.x * 256 + tid;
    int v = (i < nN) ? deg[i] : 0;
    s[tid] = v;
    __syncthreads();
#pragma unroll
    for (int o = 1; o < 256; o <<= 1) {
        int t = (tid >= o) ? s[tid - o] : 0;
        __syncthreads();
        s[tid] += t;
        __syncthreads();
    }
    if (i < nN) rowptr[i] = s[tid] - v;          // exclusive, block-local
    if (tid == 255) bsum[blockIdx.x] = s[255];   // block total
}

// ---------------------------------------------------------------- scan step 2: scan block totals (single block, carry loop)
__global__ void k_scan2(int* __restrict__ bsum, int nb) {
    __shared__ int s[512];
    __shared__ int carry_s;
    int tid = threadIdx.x;
    if (tid == 0) carry_s = 0;
    __syncthreads();
    for (int base = 0; base < nb; base += 512) {
        int i = base + tid;
        int v = (i < nb) ? bsum[i] : 0;
        s[tid] = v;
        __syncthreads();
#pragma unroll
        for (int o = 1; o < 512; o <<= 1) {
            int t = (tid >= o) ? s[tid - o] : 0;
            __syncthreads();
            s[tid] += t;
            __syncthreads();
        }
        int carry = carry_s;
        if (i < nb) bsum[i] = s[tid] - v + carry;   // exclusive global
        int total = s[511];
        __syncthreads();
        if (tid == 0) carry_s = carry + total;
        __syncthreads();
    }
}

// ---------------------------------------------------------------- scan step 3: add block offsets; init cursor; cap rowptr
__global__ void k_scan3(int* __restrict__ rowptr, const int* __restrict__ bsum,
                        int* __restrict__ cursor, int nN, int E) {
    int i = blockIdx.x * 256 + threadIdx.x;
    if (i < nN) {
        int r = rowptr[i] + bsum[blockIdx.x];
        rowptr[i] = r;
        cursor[i] = r;
    }
    if (i == 0) rowptr[nN] = E;
}

// ---------------------------------------------------------------- place edges into CSR col array
__global__ void k_place(const int* __restrict__ src, const int* __restrict__ dst,
                        int* __restrict__ cursor, int* __restrict__ col, int E) {
    int e = blockIdx.x * 256 + threadIdx.x;
    if (e < E) {
        int pos = atomicAdd(&cursor[dst[e]], 1);
        col[pos] = src[e];
    }
}

// ---------------------------------------------------------------- gather aggregation (mean), one wave per node
__global__ __launch_bounds__(256) void k_gather(
    const float* __restrict__ x, const int* __restrict__ rowptr,
    const int* __restrict__ col, float* __restrict__ agg, int nN)
{
    int node = blockIdx.x * 4 + (threadIdx.x >> 6);
    if (node >= nN) return;
    int lane = threadIdx.x & 63;
    int beg = rowptr[node], end = rowptr[node + 1];
    float ax = 0.f, ay = 0.f;
    int j = beg;
    for (; j + 1 < end; j += 2) {
        int s0 = col[j], s1 = col[j + 1];
        const float2 v0 = *(const float2*)(x + (size_t)s0 * D + lane * 2);
        const float2 v1 = *(const float2*)(x + (size_t)s1 * D + lane * 2);
        ax += v0.x + v1.x;
        ay += v0.y + v1.y;
    }
    if (j < end) {
        int s0 = col[j];
        const float2 v0 = *(const float2*)(x + (size_t)s0 * D + lane * 2);
        ax += v0.x;
        ay += v0.y;
    }
    float inv = 1.0f / (float)max(end - beg, 1);
    *(float2*)(agg + (size_t)node * D + lane * 2) = make_float2(ax * inv, ay * inv);
}

// ---------------------------------------------------------------- weight concat: Wcat[k][j], k<128 -> Wl[j][k], else Wr[j][k-128]
__global__ void k_prepw(const float* __restrict__ Wl, const float* __restrict__ Wr,
                        float* __restrict__ Wcat, int OUT) {
    int idx = blockIdx.x * 256 + threadIdx.x;
    if (idx >= 256 * OUT) return;
    int k = idx / OUT, j = idx - k * OUT;
    Wcat[idx] = (k < D) ? Wl[j * D + k] : Wr[j * D + (k - D)];
}

// ---------------------------------------------------------------- fused linear
// C[m][j] = sum_k Avirt[m][k] * Wcat[k][j] + b[j], Avirt = [agg (pre-scaled) | xin]
template<int OUT, int JT, bool RELU>
__global__ __launch_bounds__(256) void k_gemm(
    const float* agg, const float* __restrict__ xin,
    const float* __restrict__ Wcat, const float* __restrict__ bias,
    float* out, int nN)
{
    constexpr int TN = 16 * JT;
    __shared__ float As[64][65];      // [k][m], +1 pad
    __shared__ float Ws[64][TN];      // [k][j]
    const int tid = threadIdx.x;
    const int tx = tid & 15, ty = tid >> 4;
    const int m0 = blockIdx.x * 64;

    float acc[4][JT];
#pragma unroll
    for (int i = 0; i < 4; ++i)
#pragma unroll
        for (int u = 0; u < JT; ++u) acc[i][u] = 0.f;

    for (int kc = 0; kc < 4; ++kc) {
        const int k0 = kc * 64;
#pragma unroll
        for (int p = 0; p < 16; ++p) {
            int idx = tid + p * 256;           // 0..4095
            int mm = idx >> 6, kk = idx & 63;
            int node = m0 + mm;
            float v = 0.f;
            if (node < nN) {
                int k = k0 + kk;
                if (k < D) v = agg[(size_t)node * D + k];
                else       v = xin[(size_t)node * D + (k - D)];
            }
            As[kk][mm] = v;
        }
        for (int idx = tid; idx < 64 * TN; idx += 256) {
            int kk = idx / TN, j = idx - kk * TN;
            Ws[kk][j] = (j < OUT) ? Wcat[(size_t)(k0 + kk) * OUT + j] : 0.f;
        }
        __syncthreads();
#pragma unroll
        for (int kk = 0; kk < 64; ++kk) {
            float a[4];
#pragma unroll
            for (int i = 0; i < 4; ++i) a[i] = As[kk][ty * 4 + i];
#pragma unroll
            for (int u = 0; u < JT; ++u) {
                float w = Ws[kk][tx + 16 * u];
#pragma unroll
                for (int i = 0; i < 4; ++i) acc[i][u] += a[i] * w;
            }
        }
        __syncthreads();
    }
#pragma unroll
    for (int i = 0; i < 4; ++i) {
        int m = m0 + ty * 4 + i;
        if (m >= nN) continue;
#pragma unroll
        for (int u = 0; u < JT; ++u) {
            int j = tx + 16 * u;
            if (j < OUT) {
                float v = acc[i][u] + bias[j];
                if (RELU) v = fmaxf(v, 0.f);
                out[(size_t)m * OUT + j] = v;
            }
        }
    }
}

// ---------------------------------------------------------------- log_softmax over 40 cols, one wave per row
__global__ void k_logsoftmax(float* out, int nN) {
    int row = blockIdx.x * 4 + (threadIdx.x >> 6);
    int lane = threadIdx.x & 63;
    if (row >= nN) return;
    float v = (lane < 40) ? out[(size_t)row * 40 + lane] : -INFINITY;
    float mx = v;
#pragma unroll
    for (int o = 32; o; o >>= 1) mx = fmaxf(mx, __shfl_xor(mx, o));
    float e = (lane < 40) ? expf(v - mx) : 0.f;
    float s = e;
#pragma unroll
    for (int o = 32; o; o >>= 1) s += __shfl_xor(s, o);
    if (lane < 40) out[(size_t)row * 40 + lane] = v - mx - logf(s);
}

// ---------------------------------------------------------------- launch
extern "C" void kernel_launch(void* const* d_in, const int* in_sizes, int n_in,
                              void* d_out, int out_size, void* d_ws, size_t ws_size,
                              hipStream_t stream) {
    const float* x   = (const float*)d_in[0];
    const int*   ei  = (const int*)d_in[1];
    const float* Wl0 = (const float*)d_in[2];
    const float* Wr0 = (const float*)d_in[3];
    const float* b0  = (const float*)d_in[4];
    const float* Wl1 = (const float*)d_in[5];
    const float* Wr1 = (const float*)d_in[6];
    const float* b1  = (const float*)d_in[7];
    const float* Wl2 = (const float*)d_in[8];
    const float* Wr2 = (const float*)d_in[9];
    const float* b2  = (const float*)d_in[10];
    const int nN = in_sizes[0] / D;
    const int E  = in_sizes[1] / 2;
    const int* src = ei;
    const int* dst = ei + E;

    char* w = (char*)d_ws;
    auto alloc = [&](size_t bytes) { char* p = w; w += (bytes + 255) & ~(size_t)255; return p; };
    int*   deg    = (int*)  alloc((size_t)nN * 4);        // reused as cursor after scan1
    int*   rowptr = (int*)  alloc((size_t)(nN + 1) * 4);
    int*   bsum   = (int*)  alloc((size_t)((nN + 255) / 256) * 4);
    int*   col    = (int*)  alloc((size_t)E * 4);
    float* bufA   = (float*)alloc((size_t)nN * D * 4);
    float* bufB   = (float*)alloc((size_t)nN * D * 4);
    float* wcat   = (float*)alloc((size_t)256 * 128 * 4);
    float* logits = (float*)d_out;
    int*   cursor = deg;   // alias: deg is dead after k_scan1

    const int NB   = (nN + 255) / 256;
    const int GEMM_BLKS = (nN + 63) / 64;
    const int GATH_BLKS = (nN + 3) / 4;

    // ---- CSR build (once)
    hipMemsetAsync(deg, 0, (size_t)nN * 4, stream);
    k_deg  <<<(E + 255) / 256, 256, 0, stream>>>(dst, deg, E);
    k_scan1<<<NB, 256, 0, stream>>>(deg, rowptr, bsum, nN);
    k_scan2<<<1, 512, 0, stream>>>(bsum, NB);
    k_scan3<<<NB, 256, 0, stream>>>(rowptr, bsum, cursor, nN, E);
    k_place<<<(E + 255) / 256, 256, 0, stream>>>(src, dst, cursor, col, E);

    // ---- layer 0: agg(x)->bufA ; h0 = relu(lin) -> bufB
    k_gather<<<GATH_BLKS, 256, 0, stream>>>(x, rowptr, col, bufA, nN);
    k_prepw<<<(256 * 128 + 255) / 256, 256, 0, stream>>>(Wl0, Wr0, wcat, 128);
    k_gemm<128, 8, true><<<GEMM_BLKS, 256, 0, stream>>>(bufA, x, wcat, b0, bufB, nN);

    // ---- layer 1: agg(h0)->bufA ; h1 = relu(lin) -> bufA (alias-safe)
    k_gather<<<GATH_BLKS, 256, 0, stream>>>(bufB, rowptr, col, bufA, nN);
    k_prepw<<<(256 * 128 + 255) / 256, 256, 0, stream>>>(Wl1, Wr1, wcat, 128);
    k_gemm<128, 8, true><<<GEMM_BLKS, 256, 0, stream>>>(bufA, bufB, wcat, b1, bufA, nN);

    // ---- layer 2: agg(h1)->bufB ; logits = lin -> d_out ; log_softmax in place
    k_gather<<<GATH_BLKS, 256, 0, stream>>>(bufA, rowptr, col, bufB, nN);
    k_prepw<<<(256 * 40 + 255) / 256, 256, 0, stream>>>(Wl2, Wr2, wcat, 40);
    k_gemm<40, 3, false><<<GEMM_BLKS, 256, 0, stream>>>(bufB, bufA, wcat, b2, logits, nN);
    k_logsoftmax<<<(nN + 3) / 4, 256, 0, stream>>>(logits, nN);
}

// Round 3
// 418.390 us; speedup vs baseline: 7.3896x; 2.9760x over previous
//
#include <hip/hip_runtime.h>
#include <hip/hip_bf16.h>
#include <math.h>

#define D 128
typedef unsigned int uint;
typedef unsigned short ushort;

using bf16x8 = __attribute__((ext_vector_type(8))) short;
using f32x4  = __attribute__((ext_vector_type(4))) float;

static __device__ __forceinline__ ushort f2b(float f) {
    __hip_bfloat16 h = __float2bfloat16(f);
    return __builtin_bit_cast(ushort, h);
}
static __device__ __forceinline__ float b2f(ushort u) {
    uint v = ((uint)u) << 16;
    return __builtin_bit_cast(float, v);
}
static __device__ __forceinline__ float blo(uint u) {
    uint v = u << 16;
    return __builtin_bit_cast(float, v);
}
static __device__ __forceinline__ float bhi(uint u) {
    uint v = u & 0xFFFF0000u;
    return __builtin_bit_cast(float, v);
}

// ---------------------------------------------------------------- CSR build
__global__ void k_deg(const int* __restrict__ dst, int* __restrict__ deg, int E) {
    int e = blockIdx.x * 256 + threadIdx.x;
    if (e < E) atomicAdd(&deg[dst[e]], 1);
}

__global__ void k_scan1(const int* __restrict__ deg, int* __restrict__ rowptr,
                        int* __restrict__ bsum, int nN) {
    __shared__ int s[256];
    int tid = threadIdx.x;
    int i = blockIdx.x * 256 + tid;
    int v = (i < nN) ? deg[i] : 0;
    s[tid] = v;
    __syncthreads();
#pragma unroll
    for (int o = 1; o < 256; o <<= 1) {
        int t = (tid >= o) ? s[tid - o] : 0;
        __syncthreads();
        s[tid] += t;
        __syncthreads();
    }
    if (i < nN) rowptr[i] = s[tid] - v;
    if (tid == 255) bsum[blockIdx.x] = s[255];
}

__global__ void k_scan2(int* __restrict__ bsum, int nb) {
    __shared__ int s[512];
    __shared__ int carry_s;
    int tid = threadIdx.x;
    if (tid == 0) carry_s = 0;
    __syncthreads();
    for (int base = 0; base < nb; base += 512) {
        int i = base + tid;
        int v = (i < nb) ? bsum[i] : 0;
        s[tid] = v;
        __syncthreads();
#pragma unroll
        for (int o = 1; o < 512; o <<= 1) {
            int t = (tid >= o) ? s[tid - o] : 0;
            __syncthreads();
            s[tid] += t;
            __syncthreads();
        }
        int carry = carry_s;
        if (i < nb) bsum[i] = s[tid] - v + carry;
        int total = s[511];
        __syncthreads();
        if (tid == 0) carry_s = carry + total;
        __syncthreads();
    }
}

__global__ void k_scan3(int* __restrict__ rowptr, const int* __restrict__ bsum,
                        int* __restrict__ cursor, int nN, int E) {
    int i = blockIdx.x * 256 + threadIdx.x;
    if (i < nN) {
        int r = rowptr[i] + bsum[blockIdx.x];
        rowptr[i] = r;
        cursor[i] = r;
    }
    if (i == 0) rowptr[nN] = E;
}

__global__ void k_place(const int* __restrict__ src, const int* __restrict__ dst,
                        int* __restrict__ cursor, int* __restrict__ col, int E) {
    int e = blockIdx.x * 256 + threadIdx.x;
    if (e < E) {
        int pos = atomicAdd(&cursor[dst[e]], 1);
        col[pos] = src[e];
    }
}

// ---------------------------------------------------------------- x fp32 -> bf16 into Abuf cols 128..255
__global__ void k_cast(const float* __restrict__ x, ushort* __restrict__ Abuf, int n4) {
    int i = blockIdx.x * 256 + threadIdx.x;
    if (i >= n4) return;
    float4 v = *(const float4*)(x + (size_t)i * 4);
    int node = i >> 5;            // 32 float4 per 128-col row
    int coff = (i & 31) * 4;
    ushort4 o;
    o.x = f2b(v.x); o.y = f2b(v.y); o.z = f2b(v.z); o.w = f2b(v.w);
    *(ushort4*)(Abuf + (size_t)node * 256 + 128 + coff) = o;
}

// ---------------------------------------------------------------- weight prep (transposed bf16, [out_col][k])
__global__ void k_prepw1(const float* __restrict__ Wl, const float* __restrict__ Wr,
                         ushort* __restrict__ Wtg) {
    int idx = blockIdx.x * 256 + threadIdx.x;   // j*256 + k
    if (idx >= 128 * 256) return;
    int j = idx >> 8, k = idx & 255;
    float v = (k < 128) ? Wl[j * 128 + k] : Wr[j * 128 + (k - 128)];
    Wtg[idx] = f2b(v);
}

__global__ void k_prepw2(const float* __restrict__ Wl2, const float* __restrict__ Wr2,
                         ushort* __restrict__ W2tg) {
    int idx = blockIdx.x * 256 + threadIdx.x;   // j*128 + k, j<80
    if (idx >= 80 * 128) return;
    int j = idx >> 7, k = idx & 127;
    float v = (j < 40) ? Wl2[j * 128 + k] : Wr2[(j - 40) * 128 + k];
    W2tg[idx] = f2b(v);
}

// ---------------------------------------------------------------- 128-dim mean-gather (bf16 in/out), one wave per node
__global__ __launch_bounds__(256) void k_gather128(
    const ushort* __restrict__ feat, ushort* __restrict__ agg,
    const int* __restrict__ rowptr, const int* __restrict__ col, int nN)
{
    int node = blockIdx.x * 4 + (threadIdx.x >> 6);
    if (node >= nN) return;
    int lane = threadIdx.x & 63;
    int beg = rowptr[node], end = rowptr[node + 1];
    float ax = 0.f, ay = 0.f;
    int j = beg;
    for (; j + 3 < end; j += 4) {
        int s0 = col[j], s1 = col[j + 1], s2 = col[j + 2], s3 = col[j + 3];
        uint u0 = *(const uint*)(feat + (size_t)s0 * 256 + lane * 2);
        uint u1 = *(const uint*)(feat + (size_t)s1 * 256 + lane * 2);
        uint u2 = *(const uint*)(feat + (size_t)s2 * 256 + lane * 2);
        uint u3 = *(const uint*)(feat + (size_t)s3 * 256 + lane * 2);
        ax += blo(u0) + blo(u1) + blo(u2) + blo(u3);
        ay += bhi(u0) + bhi(u1) + bhi(u2) + bhi(u3);
    }
    for (; j < end; ++j) {
        uint u0 = *(const uint*)(feat + (size_t)col[j] * 256 + lane * 2);
        ax += blo(u0);
        ay += bhi(u0);
    }
    float inv = 1.0f / (float)max(end - beg, 1);
    uint packed = (uint)f2b(ax * inv) | ((uint)f2b(ay * inv) << 16);
    *(uint*)(agg + (size_t)node * 256 + lane * 2) = packed;
}

// ---------------------------------------------------------------- MFMA GEMM: C[m][j] = A[m][0..K) @ Wt[j][0..K)
// MODE 0: v += bias[j]; relu.   MODE 1: v += (j>=40 ? bias[j-40] : 0); no relu.
template<int OUTJ, int KDIM, int SW, int MODE>
__global__ __launch_bounds__(256) void k_gemm_mfma(
    const ushort* __restrict__ A, int astride,
    const ushort* __restrict__ Wt, const float* __restrict__ bias,
    ushort* __restrict__ out, int ostride, int nN)
{
    constexpr int NT = OUTJ / 16;
    constexpr int KSTEPS = KDIM / 32;
    __shared__ __align__(16) ushort Ws[OUTJ * SW];

    const int tid = threadIdx.x;
    // stage Wt -> LDS (row stride SW, SW*2 bytes is 16B-aligned; SW/2 mod 32 == 4 -> 2-way max)
    constexpr int CHUNKS = OUTJ * KDIM / 8;
#pragma unroll
    for (int c = tid; c < CHUNKS; c += 256) {
        int row = c / (KDIM / 8);
        int ko  = (c % (KDIM / 8)) * 8;
        *(uint4*)(Ws + row * SW + ko) = *(const uint4*)(Wt + row * KDIM + ko);
    }
    __syncthreads();

    const int l = tid & 63, wv = tid >> 6;
    const int q = l >> 4, r = l & 15;
    const long long m0 = (long long)blockIdx.x * 128 + wv * 32;
    const int mA = (int)min(m0 + r, (long long)(nN - 1));
    const int mB = (int)min(m0 + 16 + r, (long long)(nN - 1));
    const ushort* pa = A + (size_t)mA * astride + q * 8;
    const ushort* pb = A + (size_t)mB * astride + q * 8;

    f32x4 acc[2][NT];
#pragma unroll
    for (int mt = 0; mt < 2; ++mt)
#pragma unroll
        for (int nt = 0; nt < NT; ++nt)
            acc[mt][nt] = (f32x4){0.f, 0.f, 0.f, 0.f};

    bf16x8 a0 = *(const bf16x8*)pa;
    bf16x8 a1 = *(const bf16x8*)pb;
#pragma unroll
    for (int ks = 0; ks < KSTEPS; ++ks) {
        bf16x8 a0n = a0, a1n = a1;
        if (ks + 1 < KSTEPS) {
            a0n = *(const bf16x8*)(pa + (ks + 1) * 32);
            a1n = *(const bf16x8*)(pb + (ks + 1) * 32);
        }
#pragma unroll
        for (int nt = 0; nt < NT; ++nt) {
            bf16x8 b = *(const bf16x8*)(Ws + (nt * 16 + r) * SW + ks * 32 + q * 8);
            acc[0][nt] = __builtin_amdgcn_mfma_f32_16x16x32_bf16(a0, b, acc[0][nt], 0, 0, 0);
            acc[1][nt] = __builtin_amdgcn_mfma_f32_16x16x32_bf16(a1, b, acc[1][nt], 0, 0, 0);
        }
        a0 = a0n; a1 = a1n;
    }

    // epilogue: C layout col = lane&15, row = quad*4 + i (m89-verified)
#pragma unroll
    for (int mt = 0; mt < 2; ++mt) {
#pragma unroll
        for (int i = 0; i < 4; ++i) {
            long long m = m0 + mt * 16 + q * 4 + i;
            if (m >= nN) continue;
#pragma unroll
            for (int nt = 0; nt < NT; ++nt) {
                int cc = nt * 16 + r;
                float v = acc[mt][nt][i];
                if (MODE == 0) { v += bias[cc]; v = fmaxf(v, 0.f); }
                else           { if (cc >= 40) v += bias[cc - 40]; }
                out[(size_t)m * ostride + cc] = f2b(v);
            }
        }
    }
}

// ---------------------------------------------------------------- 40-dim gather (P) + self (R) + log_softmax, one wave per node
__global__ __launch_bounds__(256) void k_gather40_lsm(
    const ushort* __restrict__ PR, const int* __restrict__ rowptr,
    const int* __restrict__ col, float* __restrict__ out, int nN)
{
    int node = blockIdx.x * 4 + (threadIdx.x >> 6);
    if (node >= nN) return;
    int lane = threadIdx.x & 63;
    int beg = rowptr[node], end = rowptr[node + 1];
    float s = 0.f;
    if (lane < 40) {
        int j = beg;
        for (; j + 1 < end; j += 2) {
            s += b2f(PR[(size_t)col[j] * 80 + lane]) +
                 b2f(PR[(size_t)col[j + 1] * 80 + lane]);
        }
        if (j < end) s += b2f(PR[(size_t)col[j] * 80 + lane]);
        float inv = 1.0f / (float)max(end - beg, 1);
        s = s * inv + b2f(PR[(size_t)node * 80 + 40 + lane]);
    }
    float v = (lane < 40) ? s : -INFINITY;
    float mx = v;
#pragma unroll
    for (int o = 32; o; o >>= 1) mx = fmaxf(mx, __shfl_xor(mx, o));
    float e = (lane < 40) ? expf(v - mx) : 0.f;
    float sum = e;
#pragma unroll
    for (int o = 32; o; o >>= 1) sum += __shfl_xor(sum, o);
    if (lane < 40) out[(size_t)node * 40 + lane] = v - mx - logf(sum);
}

// ---------------------------------------------------------------- launch
extern "C" void kernel_launch(void* const* d_in, const int* in_sizes, int n_in,
                              void* d_out, int out_size, void* d_ws, size_t ws_size,
                              hipStream_t stream) {
    const float* x   = (const float*)d_in[0];
    const int*   ei  = (const int*)d_in[1];
    const float* Wl0 = (const float*)d_in[2];
    const float* Wr0 = (const float*)d_in[3];
    const float* b0  = (const float*)d_in[4];
    const float* Wl1 = (const float*)d_in[5];
    const float* Wr1 = (const float*)d_in[6];
    const float* b1  = (const float*)d_in[7];
    const float* Wl2 = (const float*)d_in[8];
    const float* Wr2 = (const float*)d_in[9];
    const float* b2  = (const float*)d_in[10];
    const int nN = in_sizes[0] / D;
    const int E  = in_sizes[1] / 2;
    const int* src = ei;
    const int* dst = ei + E;

    char* w = (char*)d_ws;
    auto alloc = [&](size_t bytes) { char* p = w; w += (bytes + 255) & ~(size_t)255; return p; };
    int*    deg    = (int*)   alloc((size_t)nN * 4);          // reused as cursor
    int*    rowptr = (int*)   alloc((size_t)(nN + 1) * 4);
    int*    bsum   = (int*)   alloc((size_t)((nN + 255) / 256) * 4);
    int*    col    = (int*)   alloc((size_t)E * 4);
    ushort* AbufA  = (ushort*)alloc((size_t)nN * 256 * 2);    // [agg | feat] bf16
    ushort* AbufB  = (ushort*)alloc((size_t)nN * 256 * 2);
    ushort* Wtg    = (ushort*)alloc((size_t)128 * 256 * 2);
    ushort* W2tg   = (ushort*)alloc((size_t)80 * 128 * 2);
    ushort* PR     = AbufB;   // alias: AbufB dead before GEMM2 writes PR
    float*  logits = (float*)d_out;
    int*    cursor = deg;

    const int NB        = (nN + 255) / 256;
    const int GATH_BLKS = (nN + 3) / 4;
    const int GEMM_BLKS = (nN + 127) / 128;

    // ---- CSR build
    hipMemsetAsync(deg, 0, (size_t)nN * 4, stream);
    k_deg  <<<(E + 255) / 256, 256, 0, stream>>>(dst, deg, E);
    k_scan1<<<NB, 256, 0, stream>>>(deg, rowptr, bsum, nN);
    k_scan2<<<1, 512, 0, stream>>>(bsum, NB);
    k_scan3<<<NB, 256, 0, stream>>>(rowptr, bsum, cursor, nN, E);
    k_place<<<(E + 255) / 256, 256, 0, stream>>>(src, dst, cursor, col, E);

    // ---- x -> bf16 (AbufA cols 128..255)
    k_cast<<<(nN * 32 + 255) / 256, 256, 0, stream>>>(x, AbufA, nN * 32);

    // ---- layer 0
    k_prepw1<<<128, 256, 0, stream>>>(Wl0, Wr0, Wtg);
    k_gather128<<<GATH_BLKS, 256, 0, stream>>>(AbufA + 128, AbufA, rowptr, col, nN);
    k_gemm_mfma<128, 256, 264, 0><<<GEMM_BLKS, 256, 0, stream>>>(
        AbufA, 256, Wtg, b0, AbufB + 128, 256, nN);

    // ---- layer 1
    k_prepw1<<<128, 256, 0, stream>>>(Wl1, Wr1, Wtg);
    k_gather128<<<GATH_BLKS, 256, 0, stream>>>(AbufB + 128, AbufB, rowptr, col, nN);
    k_gemm_mfma<128, 256, 264, 0><<<GEMM_BLKS, 256, 0, stream>>>(
        AbufB, 256, Wtg, b1, AbufA + 128, 256, nN);   // h1 -> AbufA cols 128+

    // ---- layer 2: project first (linearity of mean), then 40-dim gather + log_softmax
    k_prepw2<<<40, 256, 0, stream>>>(Wl2, Wr2, W2tg);
    k_gemm_mfma<80, 128, 136, 1><<<GEMM_BLKS, 256, 0, stream>>>(
        AbufA + 128, 256, W2tg, b2, PR, 80, nN);      // [P | R+b2] bf16
    k_gather40_lsm<<<GATH_BLKS, 256, 0, stream>>>(PR, rowptr, col, logits, nN);
}

// Round 4
// 380.028 us; speedup vs baseline: 8.1355x; 1.1009x over previous
//
#include <hip/hip_runtime.h>
#include <hip/hip_bf16.h>
#include <math.h>

#define D 128
typedef unsigned int uint;
typedef unsigned short ushort;

using bf16x8 = __attribute__((ext_vector_type(8))) short;
using f32x4  = __attribute__((ext_vector_type(4))) float;

static __device__ __forceinline__ ushort f2b(float f) {
    __hip_bfloat16 h = __float2bfloat16(f);
    return __builtin_bit_cast(ushort, h);
}
static __device__ __forceinline__ float blo(uint u) {
    uint v = u << 16;
    return __builtin_bit_cast(float, v);
}
static __device__ __forceinline__ float bhi(uint u) {
    uint v = u & 0xFFFF0000u;
    return __builtin_bit_cast(float, v);
}

// ---------------------------------------------------------------- CSR build
__global__ void k_deg(const int* __restrict__ dst, int* __restrict__ deg, int E) {
    int e = blockIdx.x * 256 + threadIdx.x;
    if (e < E) atomicAdd(&deg[dst[e]], 1);
}

__global__ void k_scan1(const int* __restrict__ deg, int* __restrict__ rowptr,
                        int* __restrict__ bsum, int nN) {
    __shared__ int s[256];
    int tid = threadIdx.x;
    int i = blockIdx.x * 256 + tid;
    int v = (i < nN) ? deg[i] : 0;
    s[tid] = v;
    __syncthreads();
#pragma unroll
    for (int o = 1; o < 256; o <<= 1) {
        int t = (tid >= o) ? s[tid - o] : 0;
        __syncthreads();
        s[tid] += t;
        __syncthreads();
    }
    if (i < nN) rowptr[i] = s[tid] - v;
    if (tid == 255) bsum[blockIdx.x] = s[255];
}

__global__ void k_scan2(int* __restrict__ bsum, int nb) {
    __shared__ int s[512];
    __shared__ int carry_s;
    int tid = threadIdx.x;
    if (tid == 0) carry_s = 0;
    __syncthreads();
    for (int base = 0; base < nb; base += 512) {
        int i = base + tid;
        int v = (i < nb) ? bsum[i] : 0;
        s[tid] = v;
        __syncthreads();
#pragma unroll
        for (int o = 1; o < 512; o <<= 1) {
            int t = (tid >= o) ? s[tid - o] : 0;
            __syncthreads();
            s[tid] += t;
            __syncthreads();
        }
        int carry = carry_s;
        if (i < nb) bsum[i] = s[tid] - v + carry;
        int total = s[511];
        __syncthreads();
        if (tid == 0) carry_s = carry + total;
        __syncthreads();
    }
}

__global__ void k_scan3(int* __restrict__ rowptr, const int* __restrict__ bsum,
                        int* __restrict__ cursor, int nN, int E) {
    int i = blockIdx.x * 256 + threadIdx.x;
    if (i < nN) {
        int r = rowptr[i] + bsum[blockIdx.x];
        rowptr[i] = r;
        cursor[i] = r;
    }
    if (i == 0) rowptr[nN] = E;
}

__global__ void k_place(const int* __restrict__ src, const int* __restrict__ dst,
                        int* __restrict__ cursor, int* __restrict__ col, int E) {
    int e = blockIdx.x * 256 + threadIdx.x;
    if (e < E) {
        int pos = atomicAdd(&cursor[dst[e]], 1);
        col[pos] = src[e];
    }
}

// ---------------------------------------------------------------- x fp32 -> bf16 into Abuf cols 128..255
__global__ void k_cast(const float* __restrict__ x, ushort* __restrict__ Abuf, int n4) {
    int i = blockIdx.x * 256 + threadIdx.x;
    if (i >= n4) return;
    float4 v = *(const float4*)(x + (size_t)i * 4);
    int node = i >> 5;
    int coff = (i & 31) * 4;
    ushort4 o;
    o.x = f2b(v.x); o.y = f2b(v.y); o.z = f2b(v.z); o.w = f2b(v.w);
    *(ushort4*)(Abuf + (size_t)node * 256 + 128 + coff) = o;
}

// ---------------------------------------------------------------- all weight prep in one launch
// idx space: [0, 2*128*256) -> Wtg0/Wtg1 ; [2*128*256, +80*128) -> W2tg
__global__ void k_prepw(const float* __restrict__ Wl0, const float* __restrict__ Wr0,
                        const float* __restrict__ Wl1, const float* __restrict__ Wr1,
                        const float* __restrict__ Wl2, const float* __restrict__ Wr2,
                        ushort* __restrict__ Wtg0, ushort* __restrict__ Wtg1,
                        ushort* __restrict__ W2tg) {
    int idx = blockIdx.x * 256 + threadIdx.x;
    if (idx < 2 * 128 * 256) {
        int which = idx >> 15;           // 0 or 1
        int o = idx & 32767;             // j*256 + k
        int j = o >> 8, k = o & 255;
        const float* Wl = which ? Wl1 : Wl0;
        const float* Wr = which ? Wr1 : Wr0;
        float v = (k < 128) ? Wl[j * 128 + k] : Wr[j * 128 + (k - 128)];
        (which ? Wtg1 : Wtg0)[o] = f2b(v);
    } else {
        int o = idx - 2 * 128 * 256;     // j*128 + k, j<80
        if (o >= 80 * 128) return;
        int j = o >> 7, k = o & 127;
        float v = (j < 40) ? Wl2[j * 128 + k] : Wr2[(j - 40) * 128 + k];
        W2tg[o] = f2b(v);
    }
}

// ---------------------------------------------------------------- 128-dim mean-gather, 4 edges/wave-iter, dwordx4 loads
__global__ __launch_bounds__(256) void k_gather128(
    const ushort* __restrict__ feat, ushort* __restrict__ agg,
    const int* __restrict__ rowptr, const int* __restrict__ col, int nN)
{
    int node = blockIdx.x * 4 + (threadIdx.x >> 6);
    if (node >= nN) return;
    int lane = threadIdx.x & 63;
    int g = lane >> 4;          // edge slot 0..3
    int r = lane & 15;          // 16B chunk -> cols 8r..8r+7
    int beg = rowptr[node], end = rowptr[node + 1];
    float a[8];
#pragma unroll
    for (int i = 0; i < 8; ++i) a[i] = 0.f;

    int j = beg + g;
    for (; j + 4 < end; j += 8) {          // 8 edges per unrolled iter (2 per group)
        int s0 = col[j], s1 = col[j + 4];
        uint4 v0 = *(const uint4*)(feat + (size_t)s0 * 256 + r * 8);
        uint4 v1 = *(const uint4*)(feat + (size_t)s1 * 256 + r * 8);
        const uint* p0 = (const uint*)&v0;
        const uint* p1 = (const uint*)&v1;
#pragma unroll
        for (int i = 0; i < 4; ++i) {
            a[2 * i]     += blo(p0[i]) + blo(p1[i]);
            a[2 * i + 1] += bhi(p0[i]) + bhi(p1[i]);
        }
    }
    if (j < end) {
        int s0 = col[j];
        uint4 v0 = *(const uint4*)(feat + (size_t)s0 * 256 + r * 8);
        const uint* p0 = (const uint*)&v0;
#pragma unroll
        for (int i = 0; i < 4; ++i) {
            a[2 * i]     += blo(p0[i]);
            a[2 * i + 1] += bhi(p0[i]);
        }
    }
#pragma unroll
    for (int i = 0; i < 8; ++i) {
        a[i] += __shfl_xor(a[i], 16);
        a[i] += __shfl_xor(a[i], 32);
    }
    if (g == 0) {
        float inv = 1.0f / (float)max(end - beg, 1);
        uint4 o;
        uint* po = (uint*)&o;
#pragma unroll
        for (int i = 0; i < 4; ++i)
            po[i] = (uint)f2b(a[2 * i] * inv) | ((uint)f2b(a[2 * i + 1] * inv) << 16);
        *(uint4*)(agg + (size_t)node * 256 + r * 8) = o;
    }
}

// ---------------------------------------------------------------- MFMA GEMM
// MODE 0: v += bias[j]; relu; out[m*ostride+j].
// MODE 1: j<40 -> P=out[m*40+j]; j>=40 -> R=out2[m*40+j-40] + bias[j-40].
template<int OUTJ, int KDIM, int SW, int MODE>
__global__ __launch_bounds__(256) void k_gemm_mfma(
    const ushort* __restrict__ A, int astride,
    const ushort* __restrict__ Wt, const float* __restrict__ bias,
    ushort* __restrict__ out, int ostride, ushort* __restrict__ out2, int nN)
{
    constexpr int NT = OUTJ / 16;
    constexpr int KSTEPS = KDIM / 32;
    __shared__ __align__(16) ushort Ws[OUTJ * SW];

    const int tid = threadIdx.x;
    constexpr int CHUNKS = OUTJ * KDIM / 8;
#pragma unroll
    for (int c = tid; c < CHUNKS; c += 256) {
        int row = c / (KDIM / 8);
        int ko  = (c % (KDIM / 8)) * 8;
        *(uint4*)(Ws + row * SW + ko) = *(const uint4*)(Wt + row * KDIM + ko);
    }
    __syncthreads();

    const int l = tid & 63, wv = tid >> 6;
    const int q = l >> 4, r = l & 15;
    const long long m0 = (long long)blockIdx.x * 128 + wv * 32;
    const int mA = (int)min(m0 + r, (long long)(nN - 1));
    const int mB = (int)min(m0 + 16 + r, (long long)(nN - 1));
    const ushort* pa = A + (size_t)mA * astride + q * 8;
    const ushort* pb = A + (size_t)mB * astride + q * 8;

    f32x4 acc[2][NT];
#pragma unroll
    for (int mt = 0; mt < 2; ++mt)
#pragma unroll
        for (int nt = 0; nt < NT; ++nt)
            acc[mt][nt] = (f32x4){0.f, 0.f, 0.f, 0.f};

    bf16x8 a0 = *(const bf16x8*)pa;
    bf16x8 a1 = *(const bf16x8*)pb;
#pragma unroll
    for (int ks = 0; ks < KSTEPS; ++ks) {
        bf16x8 a0n = a0, a1n = a1;
        if (ks + 1 < KSTEPS) {
            a0n = *(const bf16x8*)(pa + (ks + 1) * 32);
            a1n = *(const bf16x8*)(pb + (ks + 1) * 32);
        }
#pragma unroll
        for (int nt = 0; nt < NT; ++nt) {
            bf16x8 b = *(const bf16x8*)(Ws + (nt * 16 + r) * SW + ks * 32 + q * 8);
            acc[0][nt] = __builtin_amdgcn_mfma_f32_16x16x32_bf16(a0, b, acc[0][nt], 0, 0, 0);
            acc[1][nt] = __builtin_amdgcn_mfma_f32_16x16x32_bf16(a1, b, acc[1][nt], 0, 0, 0);
        }
        a0 = a0n; a1 = a1n;
    }

#pragma unroll
    for (int mt = 0; mt < 2; ++mt) {
#pragma unroll
        for (int i = 0; i < 4; ++i) {
            long long m = m0 + mt * 16 + q * 4 + i;
            if (m >= nN) continue;
#pragma unroll
            for (int nt = 0; nt < NT; ++nt) {
                int cc = nt * 16 + r;
                float v = acc[mt][nt][i];
                if (MODE == 0) {
                    v += bias[cc];
                    v = fmaxf(v, 0.f);
                    out[(size_t)m * ostride + cc] = f2b(v);
                } else {
                    if (cc < 40) out[(size_t)m * 40 + cc] = f2b(v);
                    else { v += bias[cc - 40]; out2[(size_t)m * 40 + (cc - 40)] = f2b(v); }
                }
            }
        }
    }
}

// ---------------------------------------------------------------- 40-dim mean-gather + self + log_softmax
// P packed [N,40] bf16; 8 edges/wave-iter, 8 lanes x 16B per edge (r>=5 reads
// spill into next row: finite garbage, masked at softmax).
__global__ __launch_bounds__(256) void k_gather40_lsm(
    const ushort* __restrict__ P, const ushort* __restrict__ R,
    const int* __restrict__ rowptr, const int* __restrict__ col,
    float* __restrict__ out, int nN)
{
    int node = blockIdx.x * 4 + (threadIdx.x >> 6);
    if (node >= nN) return;
    int lane = threadIdx.x & 63;
    int g = lane >> 3;          // edge slot 0..7
    int r = lane & 7;           // 16B chunk -> cols 8r..8r+7 (valid r<5)
    int beg = rowptr[node], end = rowptr[node + 1];
    float a[8];
#pragma unroll
    for (int i = 0; i < 8; ++i) a[i] = 0.f;

    for (int j = beg + g; j < end; j += 8) {
        int s = col[j];
        uint4 v = *(const uint4*)(P + (size_t)s * 40 + r * 8);
        const uint* p = (const uint*)&v;
#pragma unroll
        for (int i = 0; i < 4; ++i) {
            a[2 * i]     += blo(p[i]);
            a[2 * i + 1] += bhi(p[i]);
        }
    }
#pragma unroll
    for (int i = 0; i < 8; ++i) {
        a[i] += __shfl_xor(a[i], 8);
        a[i] += __shfl_xor(a[i], 16);
        a[i] += __shfl_xor(a[i], 32);
    }
    float inv = 1.0f / (float)max(end - beg, 1);
    uint4 rv = *(const uint4*)(R + (size_t)node * 40 + r * 8);
    const uint* pr = (const uint*)&rv;
    float vv[8];
    float mx = -INFINITY;
#pragma unroll
    for (int i = 0; i < 8; ++i) {
        float rc = (i & 1) ? bhi(pr[i >> 1]) : blo(pr[i >> 1]);
        int c = r * 8 + i;
        vv[i] = (c < 40) ? (a[i] * inv + rc) : -INFINITY;
        mx = fmaxf(mx, vv[i]);
    }
    mx = fmaxf(mx, __shfl_xor(mx, 1));
    mx = fmaxf(mx, __shfl_xor(mx, 2));
    mx = fmaxf(mx, __shfl_xor(mx, 4));
    float s = 0.f;
#pragma unroll
    for (int i = 0; i < 8; ++i) {
        int c = r * 8 + i;
        if (c < 40) s += __expf(vv[i] - mx);
    }
    s += __shfl_xor(s, 1);
    s += __shfl_xor(s, 2);
    s += __shfl_xor(s, 4);
    float lse = mx + __logf(s);
    if (g == 0 && r < 5) {
        float4 o0 = make_float4(vv[0] - lse, vv[1] - lse, vv[2] - lse, vv[3] - lse);
        float4 o1 = make_float4(vv[4] - lse, vv[5] - lse, vv[6] - lse, vv[7] - lse);
        *(float4*)(out + (size_t)node * 40 + r * 8)     = o0;
        *(float4*)(out + (size_t)node * 40 + r * 8 + 4) = o1;
    }
}

// ---------------------------------------------------------------- launch
extern "C" void kernel_launch(void* const* d_in, const int* in_sizes, int n_in,
                              void* d_out, int out_size, void* d_ws, size_t ws_size,
                              hipStream_t stream) {
    const float* x   = (const float*)d_in[0];
    const int*   ei  = (const int*)d_in[1];
    const float* Wl0 = (const float*)d_in[2];
    const float* Wr0 = (const float*)d_in[3];
    const float* b0  = (const float*)d_in[4];
    const float* Wl1 = (const float*)d_in[5];
    const float* Wr1 = (const float*)d_in[6];
    const float* b1  = (const float*)d_in[7];
    const float* Wl2 = (const float*)d_in[8];
    const float* Wr2 = (const float*)d_in[9];
    const float* b2  = (const float*)d_in[10];
    const int nN = in_sizes[0] / D;
    const int E  = in_sizes[1] / 2;
    const int* src = ei;
    const int* dst = ei + E;

    char* w = (char*)d_ws;
    auto alloc = [&](size_t bytes) { char* p = w; w += (bytes + 255) & ~(size_t)255; return p; };
    int*    deg    = (int*)   alloc((size_t)nN * 4);          // reused as cursor
    int*    rowptr = (int*)   alloc((size_t)(nN + 1) * 4);
    int*    bsum   = (int*)   alloc((size_t)((nN + 255) / 256) * 4);
    int*    col    = (int*)   alloc((size_t)E * 4);
    ushort* AbufA  = (ushort*)alloc((size_t)nN * 256 * 2);    // [agg | feat] bf16
    ushort* AbufB  = (ushort*)alloc((size_t)nN * 256 * 2);
    ushort* Wtg0   = (ushort*)alloc((size_t)128 * 256 * 2);
    ushort* Wtg1   = (ushort*)alloc((size_t)128 * 256 * 2);
    ushort* W2tg   = (ushort*)alloc((size_t)80 * 128 * 2);
    // P/R alias into AbufB (dead after layer-1 GEMM reads it)
    ushort* Pbuf   = AbufB;                    // [N,40] bf16 packed
    ushort* Rbuf   = AbufB + (size_t)nN * 40;  // [N,40] bf16 (8MB offset, 128B-aligned)
    float*  logits = (float*)d_out;
    int*    cursor = deg;

    const int NB        = (nN + 255) / 256;
    const int GATH_BLKS = (nN + 3) / 4;
    const int GEMM_BLKS = (nN + 127) / 128;
    const int PREPW_TOT = 2 * 128 * 256 + 80 * 128;

    // ---- CSR build + casts + weight prep
    hipMemsetAsync(deg, 0, (size_t)nN * 4, stream);
    k_deg  <<<(E + 255) / 256, 256, 0, stream>>>(dst, deg, E);
    k_scan1<<<NB, 256, 0, stream>>>(deg, rowptr, bsum, nN);
    k_scan2<<<1, 512, 0, stream>>>(bsum, NB);
    k_scan3<<<NB, 256, 0, stream>>>(rowptr, bsum, cursor, nN, E);
    k_place<<<(E + 255) / 256, 256, 0, stream>>>(src, dst, cursor, col, E);
    k_cast <<<(nN * 32 + 255) / 256, 256, 0, stream>>>(x, AbufA, nN * 32);
    k_prepw<<<(PREPW_TOT + 255) / 256, 256, 0, stream>>>(
        Wl0, Wr0, Wl1, Wr1, Wl2, Wr2, Wtg0, Wtg1, W2tg);

    // ---- layer 0
    k_gather128<<<GATH_BLKS, 256, 0, stream>>>(AbufA + 128, AbufA, rowptr, col, nN);
    k_gemm_mfma<128, 256, 264, 0><<<GEMM_BLKS, 256, 0, stream>>>(
        AbufA, 256, Wtg0, b0, AbufB + 128, 256, nullptr, nN);

    // ---- layer 1
    k_gather128<<<GATH_BLKS, 256, 0, stream>>>(AbufB + 128, AbufB, rowptr, col, nN);
    k_gemm_mfma<128, 256, 264, 0><<<GEMM_BLKS, 256, 0, stream>>>(
        AbufB, 256, Wtg1, b1, AbufA + 128, 256, nullptr, nN);   // h1 -> AbufA cols 128+

    // ---- layer 2: project first, then 40-dim gather + log_softmax
    k_gemm_mfma<80, 128, 136, 1><<<GEMM_BLKS, 256, 0, stream>>>(
        AbufA + 128, 256, W2tg, b2, Pbuf, 40, Rbuf, nN);
    k_gather40_lsm<<<GATH_BLKS, 256, 0, stream>>>(Pbuf, Rbuf, rowptr, col, logits, nN);
}